// Round 1
// baseline (28.164 us; speedup 1.0000x reference)
//
#include <hip/hip_runtime.h>

#define S_DIM 4096
#define B_DIM 4096
#define TPB   256
#define COLS  2      // columns per thread (float2 loads)
#define ROWS  16     // rows per block (thread loop)

// Uniform cubic B-spline evaluation.
// grid = linspace(-2.2, 2.2, 12), h = 0.4  ->  u = (x + 2.2)/0.4 = 2.5*x + 5.5
// interval j = floor(u) clamped to [3,7]; p = j-3 in [0,4]; f = u - j in [0,1)
// nonzero bases (indices p..p+3 into the 8 coefficients):
//   w0=(1-f)^3/6  w1=(3f^3-6f^2+4)/6  w2=(-3f^3+3f^2+3f+1)/6  w3=f^3/6
__device__ __forceinline__ float bspline_eval(float xv, const float* c) {
    float u  = __builtin_fmaf(xv, 2.5f, 5.5f);
    float jf = floorf(u);
    jf = fminf(fmaxf(jf, 3.0f), 7.0f);
    float f  = u - jf;
    int   p  = (int)jf - 3;              // 0..4
    float f2 = f * f;
    float f3 = f2 * f;
    float om = 1.0f - f;
    float w0 = om * om * om * (1.0f / 6.0f);
    float w3 = f3 * (1.0f / 6.0f);
    float w1 = __builtin_fmaf(0.5f, f3, (2.0f / 3.0f) - f2);
    float w2 = 1.0f - w0 - w1 - w3;      // partition of unity

    // Select the window c[p..p+3] from 8 registers: shift-4 / shift-2 / shift-1.
    bool p4 = p >= 4;                    // p == 4
    bool p2 = (p & 2) != 0;
    bool p1 = (p & 1) != 0;
    float t0 = p4 ? c[4] : c[0];
    float t1 = p4 ? c[5] : c[1];
    float t2 = p4 ? c[6] : c[2];
    float t3 = p4 ? c[7] : c[3];
    float t4 = c[4], t5 = c[5], t6 = c[6];   // only needed when !p4
    float u0 = p2 ? t2 : t0;
    float u1 = p2 ? t3 : t1;
    float u2 = p2 ? t4 : t2;
    float u3 = p2 ? t5 : t3;
    float u4 = p2 ? t6 : t4;
    float g0 = p1 ? u1 : u0;
    float g1 = p1 ? u2 : u1;
    float g2 = p1 ? u3 : u2;
    float g3 = p1 ? u4 : u3;

    return __builtin_fmaf(w0, g0,
           __builtin_fmaf(w1, g1,
           __builtin_fmaf(w2, g2, w3 * g3)));
}

__global__ __launch_bounds__(TPB) void BSplineBasis_70446053589597_kernel(
    const float* __restrict__ x,
    const float* __restrict__ coef,
    float* __restrict__ out)
{
    const int s0 = (blockIdx.x * TPB + threadIdx.x) * COLS;   // 2 consecutive columns
    const int b0 = blockIdx.y * ROWS;

    // Load this thread's 2 coefficient rows (8 floats each) once; reuse over ROWS rows.
    const float4 a0 = *reinterpret_cast<const float4*>(coef + (size_t)s0 * 8);
    const float4 a1 = *reinterpret_cast<const float4*>(coef + (size_t)s0 * 8 + 4);
    const float4 b0v = *reinterpret_cast<const float4*>(coef + (size_t)s0 * 8 + 8);
    const float4 b1v = *reinterpret_cast<const float4*>(coef + (size_t)s0 * 8 + 12);
    const float cA[8] = {a0.x, a0.y, a0.z, a0.w, a1.x, a1.y, a1.z, a1.w};
    const float cB[8] = {b0v.x, b0v.y, b0v.z, b0v.w, b1v.x, b1v.y, b1v.z, b1v.w};

    #pragma unroll 4
    for (int r = 0; r < ROWS; ++r) {
        const size_t off = (size_t)(b0 + r) * S_DIM + s0;
        const float2 xv = *reinterpret_cast<const float2*>(x + off);
        float2 ov;
        ov.x = bspline_eval(xv.x, cA);
        ov.y = bspline_eval(xv.y, cB);
        *reinterpret_cast<float2*>(out + off) = ov;
    }
}

extern "C" void kernel_launch(void* const* d_in, const int* in_sizes, int n_in,
                              void* d_out, int out_size, void* d_ws, size_t ws_size,
                              hipStream_t stream) {
    const float* x    = (const float*)d_in[0];
    const float* coef = (const float*)d_in[1];
    // d_in[2] = grid: uniform linspace(-2.2, 2.2, 12); constants folded into the kernel.
    float* out = (float*)d_out;

    dim3 block(TPB);
    dim3 grid(S_DIM / (TPB * COLS), B_DIM / ROWS);   // (8, 256) = 2048 blocks
    BSplineBasis_70446053589597_kernel<<<grid, block, 0, stream>>>(x, coef, out);
}